// Round 18
// baseline (55.304 us; speedup 1.0000x reference)
//
#include <hip/hip_runtime.h>
#include <math.h>

#define D 64
#define C 22
#define GRID 16
#define NCELL (GRID * GRID * GRID)   // 4096
#define HCELL 0.0625f                // 1/GRID
#define TLP 24                       // padded logit row
#define K 8                          // students per batch (cell mean ~4)
#define TEMP_F 2.0f
#define KL_W_F 0.2f

// Monotonic, bijective float->uint order transform (d2 >= 0, no NaNs stored)
__device__ __forceinline__ unsigned ord_of(float d) {
    unsigned b = __float_as_uint(d);
    return (b & 0x80000000u) ? ~b : (b | 0x80000000u);
}
__device__ __forceinline__ float bfly_max32(float v) {
#pragma unroll
    for (int off = 16; off; off >>= 1) v = fmaxf(v, __shfl_xor(v, off));
    return v;
}
__device__ __forceinline__ float bfly_sum32(float v) {
#pragma unroll
    for (int off = 16; off; off >>= 1) v += __shfl_xor(v, off);
    return v;
}
__device__ __forceinline__ unsigned long long bfly_min64(unsigned long long v) {
#pragma unroll
    for (int off = 32; off; off >>= 1) {
        unsigned long long o = __shfl_xor(v, off);
        v = (o < v) ? o : v;
    }
    return v;
}
__device__ __forceinline__ int cell_of(float x, float y, float z) {
    int cx = min(GRID - 1, (int)(x * GRID));
    int cy = min(GRID - 1, (int)(y * GRID));
    int cz = min(GRID - 1, (int)(z * GRID));
    return (cz * GRID + cy) * GRID + cx;
}

// ---------------------------------------------------------------- logits role
__device__ __forceinline__ void logits_role(
        const float* __restrict__ feat, const float* __restrict__ W,
        const float* __restrict__ bias, float* __restrict__ olog,
        float* smem, int row0, int N)
{
    float* w = smem;                                   // C*D floats
    float* b = smem + C * D;
    for (int k = threadIdx.x; k < C * D; k += 256) w[k] = W[k];
    if (threadIdx.x < C) b[threadIdx.x] = bias[threadIdx.x];
    __syncthreads();

    int i = row0 + threadIdx.x;
    if (i >= N) return;

    float4 f[D / 4];
    const float4* fr = reinterpret_cast<const float4*>(feat + (size_t)i * D);
#pragma unroll
    for (int k = 0; k < D / 4; ++k) f[k] = fr[k];

    float* row = olog + (size_t)i * TLP;
#pragma unroll
    for (int c = 0; c < C; ++c) {
        float a = b[c];
        const float4* wr = reinterpret_cast<const float4*>(&w[c * D]);
#pragma unroll
        for (int k = 0; k < D / 4; ++k) {
            float4 wv = wr[k];
            a = fmaf(f[k].x, wv.x, a);
            a = fmaf(f[k].y, wv.y, a);
            a = fmaf(f[k].z, wv.z, a);
            a = fmaf(f[k].w, wv.w, a);
        }
        row[c] = a;
    }
}

// ================================================================ build kernel
// [0,64): teacher links  [64,128): student links  [128,192): tlog  [192,256): slog
// Init-free: traversal treats any index outside [0,N) as terminator; in-range
// garbage heads jump into this call's acyclic forest (terminates, superset-min
// unchanged). head tables are reset to -1 by main's last block for next call.
__global__ void __launch_bounds__(256) build_kernel(
        const float* __restrict__ tc,      // [Nt][3]
        const float* __restrict__ sc,      // [Ns][3]
        const float* __restrict__ t_feat,  // [Nt][D]
        const float* __restrict__ s_feat,  // [Ns][D]
        const float* __restrict__ Wt, const float* __restrict__ bt,
        const float* __restrict__ Ws, const float* __restrict__ bs_,
        int*    __restrict__ head_t,       // [NCELL]
        int*    __restrict__ head_s,       // [NCELL]
        float4* __restrict__ tc4,          // [Nt] (x,y,z, next-as-bits)
        float4* __restrict__ sc4,          // [Ns] (x,y,z, next-as-bits)
        float*  __restrict__ tlog, float* __restrict__ slog,
        float*  __restrict__ acc, unsigned* __restrict__ ct,
        int Ns, int Nt, int nlt, int nls, int ntb)
{
    __shared__ __align__(16) float smem[C * D + C];
    const int bx = blockIdx.x;

    if (bx == 0 && threadIdx.x == 0) { acc[0] = 0.f; acc[1] = 0.f; *ct = 0u; }

    if (bx < nlt) {
        int i = bx * 256 + threadIdx.x;
        if (i < Nt) {
            float x = tc[3 * i], y = tc[3 * i + 1], z = tc[3 * i + 2];
            int old = atomicExch(&head_t[cell_of(x, y, z)], i);
            tc4[i] = make_float4(x, y, z, __int_as_float(old));
        }
    } else if (bx < nlt + nls) {
        int i = (bx - nlt) * 256 + threadIdx.x;
        if (i < Ns) {
            float x = sc[3 * i], y = sc[3 * i + 1], z = sc[3 * i + 2];
            int old = atomicExch(&head_s[cell_of(x, y, z)], i);
            sc4[i] = make_float4(x, y, z, __int_as_float(old));
        }
    } else if (bx < nlt + nls + ntb) {
        logits_role(t_feat, Wt, bt, tlog, smem, (bx - nlt - nls) * 256, Nt);
    } else {
        logits_role(s_feat, Ws, bs_, slog, smem, (bx - nlt - nls - ntb) * 256, Ns);
    }
}

// ================================================================ main kernel
// ONE WAVE PER CELL (4096 = 256 blocks x 16 waves). Batch K students from the
// cell's chain into static register slots; lanes 0..26 chase the 27 neighbor
// teacher chains ONCE, scoring every visited teacher against all K students
// (amortizes hop latency 8x); packed (ord<<14|idx) butterfly min per student;
// rare per-student shell expansion; split-half CE+KL per student. Last block
// resets both head tables and finalizes.
__global__ void __launch_bounds__(1024) main_kernel(
        const int*   __restrict__ segment,  // [Ns]
        int*         __restrict__ head_t,   // [NCELL]
        int*         __restrict__ head_s,   // [NCELL]
        const float4* __restrict__ tc4,     // [Nt]
        const float4* __restrict__ sc4,     // [Ns]
        const float* __restrict__ tlog,     // [Nt][TLP]
        const float* __restrict__ slog,     // [Ns][TLP]
        float* __restrict__ acc, unsigned* __restrict__ ct,
        float* __restrict__ out, int Ns, int Nt)
{
    __shared__ float rs[16], rk[16];
    __shared__ int lastF;
    if (threadIdx.x == 0) lastF = 0;

    const int lane = threadIdx.x & 63;
    const int wv   = threadIdx.x >> 6;                // 0..15
    const int ci   = blockIdx.x * 16 + wv;            // cell id 0..4095
    const int cx0  = ci & (GRID - 1);
    const int cy0  = (ci >> 4) & (GRID - 1);
    const int cz0  = ci >> 8;

    float seg_a = 0.f, kl_a = 0.f;

    int t = head_s[ci];                               // student chain cursor
    bool more = ((unsigned)t < (unsigned)Ns);

    while (more) {
        // ---- collect up to K students (static slots; all lanes walk same chain)
        float sxx[K], syy[K], szz[K];
        int   sid[K];
        bool  sval[K];
#pragma unroll
        for (int k = 0; k < K; ++k) {
            sval[k] = ((unsigned)t < (unsigned)Ns);
            sid[k]  = t;
            sxx[k] = 0.f; syy[k] = 0.f; szz[k] = 0.f;
            if (sval[k]) {
                float4 q = sc4[t];
                sxx[k] = q.x; syy[k] = q.y; szz[k] = q.z;
                t = __float_as_int(q.w);
            }
        }
        more = ((unsigned)t < (unsigned)Ns);

        // ---- pass 1: 27-cell box, lanes 0..26, one chase scores all K
        unsigned long long pk[K];
#pragma unroll
        for (int k = 0; k < K; ++k) pk[k] = ~0ULL;

        if (lane < 27) {
            int cx = cx0 + (lane % 3) - 1;
            int cy = cy0 + ((lane / 3) % 3) - 1;
            int cz = cz0 + (lane / 9) - 1;
            if (((unsigned)cx | (unsigned)cy | (unsigned)cz) < (unsigned)GRID) {
                int tt = head_t[(cz * GRID + cy) * GRID + cx];
                while ((unsigned)tt < (unsigned)Nt) {
                    float4 q = tc4[tt];
#pragma unroll
                    for (int k = 0; k < K; ++k) {
                        if (sval[k]) {
                            float ax = q.x - sxx[k], ay = q.y - syy[k], az = q.z - szz[k];
                            float d2 = fmaf(ax, ax, fmaf(ay, ay, az * az));
                            unsigned long long cd =
                                ((unsigned long long)ord_of(d2) << 14)
                                | (unsigned long long)(unsigned)tt;
                            if (cd < pk[k]) pk[k] = cd;
                        }
                    }
                    tt = __float_as_int(q.w);
                }
            }
        }
#pragma unroll
        for (int k = 0; k < K; ++k) pk[k] = bfly_min64(pk[k]);

        // ---- per-student exact shell expansion (rare) + split-half CE/KL
#pragma unroll
        for (int k = 0; k < K; ++k) {
            if (!sval[k]) continue;                    // wave-uniform

            unsigned mo = (unsigned)(pk[k] >> 14);
            float bd2 = __uint_as_float((mo & 0x80000000u) ? (mo & 0x7FFFFFFFu) : ~mo);
            for (int r = 2; r <= GRID; ++r) {
                float rb = (float)(r - 1) * HCELL;
                if (bd2 <= rb * rb) break;             // NaN-safe: empty -> continue
                int side = 2 * r + 1, nb = side * side * side;
                for (int b0 = 0; b0 < nb; b0 += 64) {
                    int b = b0 + lane;
                    if (b < nb) {
                        int dx = b % side - r;
                        int dy = (b / side) % side - r;
                        int dz = b / (side * side) - r;
                        int ch = max(abs(dx), max(abs(dy), abs(dz)));
                        int cx = cx0 + dx, cy = cy0 + dy, cz = cz0 + dz;
                        if (ch == r &&
                            (((unsigned)cx | (unsigned)cy | (unsigned)cz) < (unsigned)GRID)) {
                            int tt = head_t[(cz * GRID + cy) * GRID + cx];
                            while ((unsigned)tt < (unsigned)Nt) {
                                float4 q = tc4[tt];
                                float ax = q.x - sxx[k], ay = q.y - syy[k], az = q.z - szz[k];
                                float d2 = fmaf(ax, ax, fmaf(ay, ay, az * az));
                                unsigned long long cd =
                                    ((unsigned long long)ord_of(d2) << 14)
                                    | (unsigned long long)(unsigned)tt;
                                if (cd < pk[k]) pk[k] = cd;
                                tt = __float_as_int(q.w);
                            }
                        }
                    }
                }
                pk[k] = bfly_min64(pk[k]);
                mo  = (unsigned)(pk[k] >> 14);
                bd2 = __uint_as_float((mo & 0x80000000u) ? (mo & 0x7FFFFFFFu) : ~mo);
            }
            const int bidx = (int)(pk[k] & 0x3FFFULL);
            const int i    = sid[k];

            // ---- split-half CE + KL (student: lanes 0..31, teacher: 32..63)
            const int half = lane >> 5;
            const int c    = lane & 31;
            float val = -INFINITY;
            if (c < C) val = half ? tlog[(size_t)bidx * TLP + c]
                                  : slog[(size_t)i * TLP + c];
            float m  = bfly_max32(val);                // m1 (lower) / mt (upper)
            float dv = val - m;                        // dlc (lower) / du (upper)
            float dlc_u = __shfl(dv, c);               // lower-half dlc

            float a0 = 0.f, a1 = 0.f;
            if (c < C) {
                if (half) {                            // teacher: u, Tc
                    float u = expf(0.5f * dv);
                    a0 = u;
                    a1 = u * 0.5f * (dv - dlc_u);
                } else {                               // student: e1, e2
                    a0 = expf(dv);
                    a1 = expf(0.5f * dv);
                }
            }
            float s0 = bfly_sum32(a0);                 // sum1 (lower) / U (upper)
            float s1 = bfly_sum32(a1);                 // sum2 (lower) / T (upper)
            float U  = __shfl(s0, 32);
            float T  = __shfl(s1, 32);
            int   sg = segment[i];
            float lsg = __shfl(dv, sg);                // lower half lane sg

            // valid on lane 0 only (harvested there)
            seg_a += logf(s0) - lsg;
            kl_a  += T / U + logf(s1) - logf(U);
        }
    }

    // ---- block reduce; last block resets head tables + finalizes
    if (lane == 0) { rs[wv] = seg_a; rk[wv] = kl_a; }
    __syncthreads();
    if (threadIdx.x == 0) {
        float s = 0.f, kk = 0.f;
#pragma unroll
        for (int w = 0; w < 16; ++w) { s += rs[w]; kk += rk[w]; }
        atomicAdd(&acc[0], s);
        atomicAdd(&acc[1], kk);
        __threadfence();
        unsigned tk = atomicAdd(ct, 1u);
        if (tk == gridDim.x - 1) lastF = 1;
    }
    __syncthreads();
    if (lastF) {
        for (int c = threadIdx.x; c < NCELL; c += 1024) { head_t[c] = -1; head_s[c] = -1; }
        if (threadIdx.x == 0) {
            float seg = atomicAdd(&acc[0], 0.f);       // coherent read
            float kl  = atomicAdd(&acc[1], 0.f);
            float seg_loss = seg / (float)Ns;
            float kl_loss  = KL_W_F * (kl / (float)Ns) * TEMP_F * TEMP_F;
            out[0] = seg_loss + kl_loss;
            out[1] = seg_loss;
            out[2] = kl_loss;
        }
    }
}

extern "C" void kernel_launch(void* const* d_in, const int* in_sizes, int n_in,
                              void* d_out, int out_size, void* d_ws, size_t ws_size,
                              hipStream_t stream)
{
    const float* s_feat  = (const float*)d_in[0];
    const float* t_feat  = (const float*)d_in[1];
    const float* s_coord = (const float*)d_in[2];
    const float* t_coord = (const float*)d_in[3];
    const float* seg_W   = (const float*)d_in[4];
    const float* seg_b   = (const float*)d_in[5];
    const float* seg_tW  = (const float*)d_in[6];
    const float* seg_tb  = (const float*)d_in[7];
    const int*   segment = (const int*)d_in[8];
    float* out = (float*)d_out;

    const int Ns = in_sizes[0] / D;
    const int Nt = in_sizes[1] / D;

    int*    head_t = (int*)d_ws;                                // [NCELL]
    int*    head_s = head_t + NCELL;                            // [NCELL]
    float4* tc4    = (float4*)(head_s + NCELL);                 // [Nt]
    float4* sc4    = tc4 + Nt;                                  // [Ns]
    float*  tlog   = (float*)(sc4 + Ns);                        // [Nt*TLP]
    float*  slog   = tlog + (size_t)Nt * TLP;                   // [Ns*TLP]
    float*  acc    = slog + (size_t)Ns * TLP;                   // [2]
    unsigned* ct   = (unsigned*)(acc + 2);

    const int nlt = (Nt + 255) / 256;                           // 64
    const int nls = (Ns + 255) / 256;                           // 64
    const int ntb = (Nt + 255) / 256;                           // 64
    const int nsb = (Ns + 255) / 256;                           // 64

    build_kernel<<<nlt + nls + ntb + nsb, 256, 0, stream>>>(
        t_coord, s_coord, t_feat, s_feat, seg_tW, seg_tb, seg_W, seg_b,
        head_t, head_s, tc4, sc4, tlog, slog, acc, ct, Ns, Nt, nlt, nls, ntb);

    main_kernel<<<(NCELL + 15) / 16, 1024, 0, stream>>>(
        segment, head_t, head_s, tc4, sc4, tlog, slog, acc, ct, out, Ns, Nt);
}

// Round 19
// 44.910 us; speedup vs baseline: 1.2314x; 1.2314x over previous
//
#include <hip/hip_runtime.h>
#include <math.h>

#define D 64
#define C 22
#define GRID 32
#define NCELL (GRID * GRID * GRID)   // 32768
#define HCELL 0.03125f               // 1/GRID
#define TLP 24                       // padded logit row
#define TEMP_F 2.0f
#define KL_W_F 0.2f

// Monotonic, bijective float->uint order transform (d2 >= 0, no NaNs stored)
__device__ __forceinline__ unsigned ord_of(float d) {
    unsigned b = __float_as_uint(d);
    return (b & 0x80000000u) ? ~b : (b | 0x80000000u);
}
__device__ __forceinline__ float bfly_max32(float v) {
#pragma unroll
    for (int off = 16; off; off >>= 1) v = fmaxf(v, __shfl_xor(v, off));
    return v;
}
__device__ __forceinline__ float bfly_sum32(float v) {
#pragma unroll
    for (int off = 16; off; off >>= 1) v += __shfl_xor(v, off);
    return v;
}
__device__ __forceinline__ unsigned long long bfly_min64(unsigned long long v) {
#pragma unroll
    for (int off = 32; off; off >>= 1) {
        unsigned long long o = __shfl_xor(v, off);
        v = (o < v) ? o : v;
    }
    return v;
}
__device__ __forceinline__ int cell_of(float x, float y, float z) {
    int cx = min(GRID - 1, (int)(x * GRID));
    int cy = min(GRID - 1, (int)(y * GRID));
    int cz = min(GRID - 1, (int)(z * GRID));
    return (cz * GRID + cy) * GRID + cx;
}

// ---------------------------------------------------------------- logits role
__device__ __forceinline__ void logits_role(
        const float* __restrict__ feat, const float* __restrict__ W,
        const float* __restrict__ bias, float* __restrict__ olog,
        float* smem, int row0, int N)
{
    float* w = smem;                                   // C*D floats
    float* b = smem + C * D;
    for (int k = threadIdx.x; k < C * D; k += 256) w[k] = W[k];
    if (threadIdx.x < C) b[threadIdx.x] = bias[threadIdx.x];
    __syncthreads();

    int i = row0 + threadIdx.x;
    if (i >= N) return;

    float4 f[D / 4];
    const float4* fr = reinterpret_cast<const float4*>(feat + (size_t)i * D);
#pragma unroll
    for (int k = 0; k < D / 4; ++k) f[k] = fr[k];

    float* row = olog + (size_t)i * TLP;
#pragma unroll
    for (int c = 0; c < C; ++c) {
        float a = b[c];
        const float4* wr = reinterpret_cast<const float4*>(&w[c * D]);
#pragma unroll
        for (int k = 0; k < D / 4; ++k) {
            float4 wv = wr[k];
            a = fmaf(f[k].x, wv.x, a);
            a = fmaf(f[k].y, wv.y, a);
            a = fmaf(f[k].z, wv.z, a);
            a = fmaf(f[k].w, wv.w, a);
        }
        row[c] = a;
    }
}

// ================================================================ build+logits
// blocks [0,64):    linked-list build — tc4[i] = (x,y,z, bits(prev head)).
// Init-free: traversal treats any index outside [0,Nt) as terminator; in-range
// garbage heads jump into this call's acyclic next-forest (terminates) and only
// ADD real-teacher candidates (superset min = exact, ties by smallest index).
// blocks [64,128):  teacher logits.  blocks [128,192): student logits.
__global__ void __launch_bounds__(256) build_kernel(
        const float* __restrict__ tc,      // [Nt][3]
        const float* __restrict__ t_feat,  // [Nt][D]
        const float* __restrict__ s_feat,  // [Ns][D]
        const float* __restrict__ Wt, const float* __restrict__ bt,
        const float* __restrict__ Ws, const float* __restrict__ bs_,
        int*    __restrict__ head,         // [NCELL] (arbitrary content OK)
        float4* __restrict__ tc4,          // [Nt] (x,y,z, next-as-bits)
        float*  __restrict__ tlog,         // [Nt][TLP]
        float*  __restrict__ slog,         // [Ns][TLP]
        float*  __restrict__ acc, unsigned* __restrict__ ct,
        int Ns, int Nt, int nlink, int ntb)
{
    __shared__ __align__(16) float smem[C * D + C];
    const int bx = blockIdx.x;

    if (bx == 0 && threadIdx.x == 0) { acc[0] = 0.f; acc[1] = 0.f; *ct = 0u; }

    if (bx < nlink) {
        int i = bx * 256 + threadIdx.x;
        if (i < Nt) {
            float x = tc[3 * i], y = tc[3 * i + 1], z = tc[3 * i + 2];
            int old = atomicExch(&head[cell_of(x, y, z)], i);
            tc4[i] = make_float4(x, y, z, __int_as_float(old));
        }
    } else if (bx < nlink + ntb) {
        logits_role(t_feat, Wt, bt, tlog, smem, (bx - nlink) * 256, Nt);
    } else {
        logits_role(s_feat, Ws, bs_, slog, smem, (bx - nlink - ntb) * 256, Ns);
    }
}

// ================================================================ main kernel
// Wave per student (grid-stride). 1-NN: 27-cell box at GRID=32 (mean 0.5
// teachers/cell -> ~1-hop chains), head read straight from L2 (no LDS copy).
// Packed (ord(d2)<<14 | idx) butterfly min; exact shell expansion while
// best_d2 > ((r-1)h)^2. Fused split-half CE+KL. Last block (ticket) resets
// head to -1 for the next call (all reads happened long before).
__global__ void __launch_bounds__(1024) main_kernel(
        const float* __restrict__ sc,       // [Ns][3]
        const int*   __restrict__ segment,  // [Ns]
        int*         __restrict__ head,     // [NCELL]
        const float4* __restrict__ tc4,     // [Nt]
        const float* __restrict__ tlog,     // [Nt][TLP]
        const float* __restrict__ slog,     // [Ns][TLP]
        float* __restrict__ acc, unsigned* __restrict__ ct,
        float* __restrict__ out, int Ns, int Nt)
{
    __shared__ float rs[16], rk[16];
    __shared__ int lastF;
    if (threadIdx.x == 0) lastF = 0;
    __syncthreads();

    const int lane   = threadIdx.x & 63;
    const int wv     = threadIdx.x >> 6;              // 0..15
    const int nwaves = gridDim.x * 16;

    float seg_a = 0.f, kl_a = 0.f;

    for (int i = blockIdx.x * 16 + wv; i < Ns; i += nwaves) {
        float sx = sc[3 * i], sy = sc[3 * i + 1], sz = sc[3 * i + 2];
        const int scx = min(GRID - 1, (int)(sx * GRID));
        const int scy = min(GRID - 1, (int)(sy * GRID));
        const int scz = min(GRID - 1, (int)(sz * GRID));

        unsigned long long pk = ~0ULL;

        // ---- pass 1: 27-cell box, one cell per lane, range-checked chase
        if (lane < 27) {
            int cx = scx + (lane % 3) - 1;
            int cy = scy + ((lane / 3) % 3) - 1;
            int cz = scz + (lane / 9) - 1;
            if (((unsigned)cx | (unsigned)cy | (unsigned)cz) < (unsigned)GRID) {
                int t = head[(cz * GRID + cy) * GRID + cx];
                while ((unsigned)t < (unsigned)Nt) {
                    float4 q = tc4[t];
                    float ax = q.x - sx, ay = q.y - sy, az = q.z - sz;
                    float d2 = fmaf(ax, ax, fmaf(ay, ay, az * az));
                    unsigned long long cd =
                        ((unsigned long long)ord_of(d2) << 14)
                        | (unsigned long long)(unsigned)t;
                    if (cd < pk) pk = cd;
                    t = __float_as_int(q.w);
                }
            }
        }
        pk = bfly_min64(pk);
        unsigned mo = (unsigned)(pk >> 14);
        float bd2 = __uint_as_float((mo & 0x80000000u) ? (mo & 0x7FFFFFFFu) : ~mo);

        // ---- exact shell expansion (cells at Chebyshev q hold points >= (q-1)h)
        for (int r = 2; r <= GRID; ++r) {
            float rb = (float)(r - 1) * HCELL;
            if (bd2 <= rb * rb) break;                // NaN-safe: empty -> continue
            int side = 2 * r + 1, nb = side * side * side;
            for (int b0 = 0; b0 < nb; b0 += 64) {
                int b = b0 + lane;
                if (b < nb) {
                    int dx = b % side - r;
                    int dy = (b / side) % side - r;
                    int dz = b / (side * side) - r;
                    int ch = max(abs(dx), max(abs(dy), abs(dz)));
                    int cx = scx + dx, cy = scy + dy, cz = scz + dz;
                    if (ch == r &&
                        (((unsigned)cx | (unsigned)cy | (unsigned)cz) < (unsigned)GRID)) {
                        int t = head[(cz * GRID + cy) * GRID + cx];
                        while ((unsigned)t < (unsigned)Nt) {
                            float4 q = tc4[t];
                            float ax = q.x - sx, ay = q.y - sy, az = q.z - sz;
                            float d2 = fmaf(ax, ax, fmaf(ay, ay, az * az));
                            unsigned long long cd =
                                ((unsigned long long)ord_of(d2) << 14)
                                | (unsigned long long)(unsigned)t;
                            if (cd < pk) pk = cd;
                            t = __float_as_int(q.w);
                        }
                    }
                }
            }
            pk = bfly_min64(pk);
            mo = (unsigned)(pk >> 14);
            bd2 = __uint_as_float((mo & 0x80000000u) ? (mo & 0x7FFFFFFFu) : ~mo);
        }
        const int bidx = (int)(pk & 0x3FFFULL);

        // ---- split-half CE + KL (student: lanes 0..31, teacher: 32..63)
        const int half = lane >> 5;
        const int c    = lane & 31;
        float val = -INFINITY;
        if (c < C) val = half ? tlog[(size_t)bidx * TLP + c]
                              : slog[(size_t)i * TLP + c];
        float m  = bfly_max32(val);                // m1 (lower) / mt (upper)
        float dv = val - m;                        // dlc (lower) / du (upper)
        float dlc_u = __shfl(dv, c);               // lower-half dlc, broadcast up

        float a0 = 0.f, a1 = 0.f;
        if (c < C) {
            if (half) {                            // teacher: u, Tc
                float u = expf(0.5f * dv);
                a0 = u;
                a1 = u * 0.5f * (dv - dlc_u);
            } else {                               // student: e1, e2
                a0 = expf(dv);
                a1 = expf(0.5f * dv);
            }
        }
        float s0 = bfly_sum32(a0);                 // sum1 (lower) / U (upper)
        float s1 = bfly_sum32(a1);                 // sum2 (lower) / T (upper)
        float U  = __shfl(s0, 32);
        float T  = __shfl(s1, 32);
        int   sg = segment[i];
        float lsg = __shfl(dv, sg);                // from lower half lane sg

        // valid on lane 0 only (harvested there)
        seg_a += logf(s0) - lsg;
        kl_a  += T / U + logf(s1) - logf(U);
    }

    // ---- block reduce, one atomic pair per block; last block resets head
    if (lane == 0) { rs[wv] = seg_a; rk[wv] = kl_a; }
    __syncthreads();
    if (threadIdx.x == 0) {
        float s = 0.f, kk = 0.f;
#pragma unroll
        for (int w = 0; w < 16; ++w) { s += rs[w]; kk += rk[w]; }
        atomicAdd(&acc[0], s);
        atomicAdd(&acc[1], kk);
        __threadfence();
        unsigned t = atomicAdd(ct, 1u);
        if (t == gridDim.x - 1) lastF = 1;
    }
    __syncthreads();
    if (lastF) {
        // every block finished its head reads before its ticket: no reader race
        for (int c = threadIdx.x; c < NCELL; c += 1024) head[c] = -1;
        if (threadIdx.x == 0) {
            float seg = atomicAdd(&acc[0], 0.f);   // coherent read
            float kl  = atomicAdd(&acc[1], 0.f);
            float seg_loss = seg / (float)Ns;
            float kl_loss  = KL_W_F * (kl / (float)Ns) * TEMP_F * TEMP_F;
            out[0] = seg_loss + kl_loss;
            out[1] = seg_loss;
            out[2] = kl_loss;
        }
    }
}

extern "C" void kernel_launch(void* const* d_in, const int* in_sizes, int n_in,
                              void* d_out, int out_size, void* d_ws, size_t ws_size,
                              hipStream_t stream)
{
    const float* s_feat  = (const float*)d_in[0];
    const float* t_feat  = (const float*)d_in[1];
    const float* s_coord = (const float*)d_in[2];
    const float* t_coord = (const float*)d_in[3];
    const float* seg_W   = (const float*)d_in[4];
    const float* seg_b   = (const float*)d_in[5];
    const float* seg_tW  = (const float*)d_in[6];
    const float* seg_tb  = (const float*)d_in[7];
    const int*   segment = (const int*)d_in[8];
    float* out = (float*)d_out;

    const int Ns = in_sizes[0] / D;
    const int Nt = in_sizes[1] / D;

    int*    head = (int*)d_ws;                                  // [NCELL]
    float4* tc4  = (float4*)(head + NCELL);                     // [Nt]
    float*  tlog = (float*)(tc4 + Nt);                          // [Nt*TLP]
    float*  slog = tlog + (size_t)Nt * TLP;                     // [Ns*TLP]
    float*  acc  = slog + (size_t)Ns * TLP;                     // [2]
    unsigned* ct = (unsigned*)(acc + 2);

    const int nlink = (Nt + 255) / 256;                         // 64
    const int ntb   = (Nt + 255) / 256;                         // 64
    const int nsb   = (Ns + 255) / 256;                         // 64

    build_kernel<<<nlink + ntb + nsb, 256, 0, stream>>>(
        t_coord, t_feat, s_feat, seg_tW, seg_tb, seg_W, seg_b,
        head, tc4, tlog, slog, acc, ct, Ns, Nt, nlink, ntb);

    main_kernel<<<256, 1024, 0, stream>>>(
        s_coord, segment, head, tc4, tlog, slog, acc, ct, out, Ns, Nt);
}